// Round 10
// baseline (1425.598 us; speedup 1.0000x reference)
//
#include <hip/hip_runtime.h>

#define BATCH   2
#define LSEQ    4096
#define DMODEL  1024
#define DINNER  2048
#define NHEADS  16
#define DSTATE  64
#define HEADDIM 128
#define ZDIM    4112
#define BLROWS  (BATCH*LSEQ)   // 8192
#define NFUSE   6400           // 4112(z)+112(pad)+2048(g)+128(pad), 25*256
#define QCHUNK  64
#define NCHUNK  (LSEQ/QCHUNK)  // 64

#define AS1 __attribute__((address_space(1)))
#define AS3 __attribute__((address_space(3)))

typedef __bf16 bf16;
typedef __bf16 bf16x8 __attribute__((ext_vector_type(8)));
typedef __bf16 bf16x4 __attribute__((ext_vector_type(4)));
typedef float  f32x4  __attribute__((ext_vector_type(4)));

// paired-row LDS swizzle for [R rows][32 bf16] regions: logical (row, 16B-chunk c) ->
// element offset. Read of 16 consecutive rows at fixed c hits 8 bank-groups x2 = free.
__device__ __forceinline__ int lds_elem(int row, int c)
{
    return (row >> 1) * 64 + (row & 1) * 32 + (((c ^ ((row >> 1) & 3)) & 3) << 3);
}

// ---------------- fp32 -> bf16 convert (vectorized) ----------------
__global__ void cvt_bf16_kernel(const float* __restrict__ in, bf16* __restrict__ out, int n)
{
    int i = (blockIdx.x * 256 + threadIdx.x) * 4;
    if (i >= n) return;
    float4 v = *reinterpret_cast<const float4*>(in + i);
    bf16x4 o;
    o[0] = (bf16)v.x; o[1] = (bf16)v.y; o[2] = (bf16)v.z; o[3] = (bf16)v.w;
    *reinterpret_cast<bf16x4*>(out + i) = o;
}

// ---------------- transpose + convert: src[R][C] f32 -> dst[Cpad][R] bf16 ----------------
__global__ void transpose_cvt_kernel(const float* __restrict__ src, bf16* __restrict__ dst,
                                     int R, int C, int Cpad)
{
    __shared__ float tile[32][33];
    int tx = threadIdx.x;   // 0..31
    int ty = threadIdx.y;   // 0..7
    int c0 = blockIdx.x * 32;
    int r0 = blockIdx.y * 32;
#pragma unroll
    for (int q = 0; q < 4; q++) {
        int r = r0 + ty + q * 8;
        int c = c0 + tx;
        float v = 0.f;
        if (r < R && c < C) v = src[(size_t)r * C + c];
        tile[ty + q * 8][tx] = v;
    }
    __syncthreads();
#pragma unroll
    for (int q = 0; q < 4; q++) {
        int oc = c0 + ty + q * 8;   // output row (= original col)
        int orr = r0 + tx;          // output col (= original row)
        if (oc < Cpad && orr < R)
            dst[(size_t)oc * R + orr] = (bf16)tile[tx][ty + q * 8];
    }
}

// ======= deep-pipelined GEMM: 256xBN tile, K-slices of 32, 2 LDS slots, 2 blocks/CU =======
// XCD supertiling: xcd = bid&7 owns bm strip [xcd*4, xcd*4+4); bn sweeps bm-fast.
// Per phase: ds_read(slot p) ; lgkmcnt(0) ; barrier [slot p dead] ; STAGE(p+2 -> slot p) ;
// MFMA ; vmcnt(L) [slot p+1 landed, stage p+2 in flight] ; barrier.
// 64KB LDS (fused) -> 2 blocks/CU: co-resident block's MFMA covers this block's LDS drain.
// MODE 0 (BN=256): fused z|g|dt epilogue.  MODE 1 (BN=128): f32 C[M][1024].
template<int NSLICE, int KROW, int MODE, int BN, int NBN>
__global__ __launch_bounds__(512, 4) void gemm8p_kernel(
    const bf16* __restrict__ A, const bf16* __restrict__ Bt,
    bf16* __restrict__ z, bf16* __restrict__ g, float* __restrict__ dtout,
    float* __restrict__ c32)
{
    constexpr int NB = BN / 64;              // B frags per wave (4 or 2)
    constexpr int SLOTSZ = (256 + BN) * 32;  // bf16 per slot
    constexpr int L = (256 + BN) / 128;      // global_load_lds per thread per stage (4 or 3)
    __shared__ __align__(16) bf16 lds[2 * SLOTSZ];
    const int tid = threadIdx.x;
    const int lane = tid & 63, wid = tid >> 6;
    const int wm = (wid >> 2) * 128, wn = (wid & 3) * (BN / 4);
    const int lml = lane & 15, kc = lane >> 4;

    // XCD supertile map: grid = 32*NBN (divisible by 8). Each XCD: 4 bm x NBN bn, bm-fast.
    const int bid = blockIdx.x;
    const int xcd = bid & 7;
    const int idx = bid >> 3;                // 0 .. 4*NBN-1
    const int bm = xcd * 4 + (idx & 3);
    const int bn = idx >> 2;                 // 0 .. NBN-1

    const bf16* Abase = A + (size_t)(bm * 256) * KROW;
    const bf16* Bbase = Bt + (size_t)bn * BN * KROW;

#define STAGE8(pp) do {                                                                  \
    const int _p = (pp); const int _slot = _p & 1; const size_t _ko = (size_t)_p * 32;   \
    _Pragma("unroll") for (int it = 0; it < L; ++it) {                                   \
        int q = it * 512 + tid;                                                          \
        const bf16* _src; int _dst;                                                      \
        if (q < 1024) {                                                                  \
            int prow = q >> 3, wi = q & 7;                                               \
            int row = prow * 2 + (wi >> 2), c = (wi & 3) ^ (prow & 3);                   \
            _src = Abase + (size_t)row * KROW + _ko + c * 8;                             \
            _dst = _slot * SLOTSZ + q * 8;                                               \
        } else {                                                                         \
            int qq = q - 1024; int prow = qq >> 3, wi = qq & 7;                          \
            int row = prow * 2 + (wi >> 2), c = (wi & 3) ^ (prow & 3);                   \
            _src = Bbase + (size_t)row * KROW + _ko + c * 8;                             \
            _dst = _slot * SLOTSZ + 8192 + qq * 8;                                       \
        }                                                                                \
        __builtin_amdgcn_global_load_lds((const AS1 void*)_src,                          \
            (AS3 void*)(&lds[_dst]), 16, 0, 0);                                          \
    }                                                                                    \
} while (0)

#define WAIT_VML() do {                                                                  \
    if constexpr (L == 4) { asm volatile("s_waitcnt vmcnt(4)" ::: "memory"); }           \
    else                  { asm volatile("s_waitcnt vmcnt(3)" ::: "memory"); }           \
} while (0)

    f32x4 acc[8][NB];
#pragma unroll
    for (int i = 0; i < 8; i++)
#pragma unroll
        for (int j = 0; j < NB; j++) acc[i][j] = (f32x4){0.f, 0.f, 0.f, 0.f};

    STAGE8(0); STAGE8(1);
    WAIT_VML();                         // slot 0 landed (slot 1 in flight)
    __builtin_amdgcn_s_barrier();

    for (int p = 0; p < NSLICE; ++p) {
        const bf16* base_ = &lds[(p & 1) * SLOTSZ];
        bf16x8 af[8], bfv[NB];
#pragma unroll
        for (int i = 0; i < 8; ++i) {
            int row = wm + i * 16 + lml;
            af[i] = *reinterpret_cast<const bf16x8*>(&base_[lds_elem(row, kc)]);
        }
#pragma unroll
        for (int j = 0; j < NB; ++j) {
            int row = wn + j * 16 + lml;
            bfv[j] = *reinterpret_cast<const bf16x8*>(&base_[8192 + lds_elem(row, kc)]);
        }
        asm volatile("s_waitcnt lgkmcnt(0)" ::: "memory");
        __builtin_amdgcn_sched_barrier(0);
        __builtin_amdgcn_s_barrier();        // slot p fully consumed by all waves
        if (p + 2 < NSLICE) STAGE8(p + 2);   // overwrite slot p&1
        __builtin_amdgcn_sched_barrier(0);
        __builtin_amdgcn_s_setprio(1);
#pragma unroll
        for (int i = 0; i < 8; ++i)
#pragma unroll
            for (int j = 0; j < NB; ++j)
                acc[i][j] = __builtin_amdgcn_mfma_f32_16x16x32_bf16(af[i], bfv[j], acc[i][j], 0, 0, 0);
        __builtin_amdgcn_s_setprio(0);
        if (p + 1 < NSLICE) {
            if (p + 2 < NSLICE) { WAIT_VML(); }                              // slot p+1 landed
            else { asm volatile("s_waitcnt vmcnt(0)" ::: "memory"); }        // final drain
            __builtin_amdgcn_s_barrier();
        }
    }
#undef STAGE8
#undef WAIT_VML

    const int rbase = (lane >> 4) * 4;
#pragma unroll
    for (int i = 0; i < 8; i++) {
#pragma unroll
        for (int j = 0; j < NB; j++) {
            int col = bn * BN + wn + j * 16 + lml;
            if constexpr (MODE == 0) {
                bool isZ = (col < ZDIM);
                bool isG = (col >= 4224) && (col < 4224 + DINNER);
                bool isDT = (col >= 4096) && (col < ZDIM);
                if (!isZ && !isG) continue;
#pragma unroll
                for (int r = 0; r < 4; r++) {
                    int row = bm * 256 + wm + i * 16 + rbase + r;
                    float v = acc[i][j][r];
                    if (isZ) {
                        z[(size_t)row * ZDIM + col] = (bf16)v;
                        if (isDT) dtout[(size_t)row * NHEADS + (col - 4096)] = v;
                    } else {
                        g[(size_t)row * DINNER + (col - 4224)] = (bf16)v;
                    }
                }
            } else {
#pragma unroll
                for (int r = 0; r < 4; r++) {
                    int row = bm * 256 + wm + i * 16 + rbase + r;
                    c32[(size_t)row * 1024 + col] = acc[i][j][r];
                }
            }
        }
    }
}

// ---------------- causal depthwise conv (D_CONV=4) + SiLU, bf16x8 vectorized ----------------
__global__ void conv_silu_kernel(const bf16* __restrict__ z, const float* __restrict__ conv_w,
                                 const float* __restrict__ conv_b, bf16* __restrict__ x)
{
    int gid = blockIdx.x * 256 + threadIdx.x;   // one thread per 8 channels
    if (gid >= BLROWS * (DINNER / 8)) return;
    int c0 = (gid & 255) * 8;
    int bl = gid >> 8;
    int l = bl & (LSEQ - 1);
    float4 wv[8];
#pragma unroll
    for (int e = 0; e < 8; e++) wv[e] = *reinterpret_cast<const float4*>(conv_w + (size_t)(c0 + e) * 4);
    float a8[8];
    {
        float4 b0 = *reinterpret_cast<const float4*>(conv_b + c0);
        float4 b1 = *reinterpret_cast<const float4*>(conv_b + c0 + 4);
        a8[0] = b0.x; a8[1] = b0.y; a8[2] = b0.z; a8[3] = b0.w;
        a8[4] = b1.x; a8[5] = b1.y; a8[6] = b1.z; a8[7] = b1.w;
    }
#pragma unroll
    for (int k = 0; k < 4; k++) {
        if (l - 3 + k >= 0) {
            bf16x8 zv = *reinterpret_cast<const bf16x8*>(z + (size_t)(bl - 3 + k) * ZDIM + c0);
            const float* wk;
#pragma unroll
            for (int e = 0; e < 8; e++) {
                wk = reinterpret_cast<const float*>(&wv[e]);
                a8[e] = fmaf((float)zv[e], wk[k], a8[e]);
            }
        }
    }
    bf16x8 o;
#pragma unroll
    for (int e = 0; e < 8; e++) o[e] = (bf16)(a8[e] / (1.f + expf(-a8[e])));
    *reinterpret_cast<bf16x8*>(x + (size_t)bl * DINNER + c0) = o;
}

// ---------------- la = log(a_bar) = -softplus(dt+dp)*|dt| ----------------
__global__ void la_kernel(const float* __restrict__ dt_in, const float* __restrict__ dparam,
                          float* __restrict__ la)
{
    int i = blockIdx.x * 256 + threadIdx.x;
    if (i >= BLROWS * NHEADS) return;
    int h = i & (NHEADS - 1);
    float dt = dt_in[i];
    float v = dt + dparam[h];
    float sp = (v > 20.f) ? v : log1pf(expf(v));
    la[i] = -sp * fabsf(dt);
}

// ================= chunked scan, SSD matmul form =================
__global__ __launch_bounds__(256) void chunk_state_kernel(
    const bf16* __restrict__ x,    // [BL][DINNER]
    const bf16* __restrict__ zb,   // B at col DINNER+h*64, stride ZDIM
    const float* __restrict__ la,  // [BL][16] log a
    bf16* __restrict__ S,          // [B][NCHUNK][NHEADS][128*64]
    float* __restrict__ Adec)      // [B][NHEADS][NCHUNK] = exp(Ls_Q)
{
    __shared__ __align__(16) bf16 xt[HEADDIM * QCHUNK]; // [d][t] swizzled
    __shared__ __align__(16) bf16 bw[DSTATE * QCHUNK];  // [s][t] swizzled, weighted
    __shared__ float Ls[QCHUNK];
    const int blk = blockIdx.x;
    const int h = blk & 15, c = (blk >> 4) & 63, b = blk >> 10;
    const int tid = threadIdx.x, lane = tid & 63, w = tid >> 6;
    const size_t row0 = (size_t)b * LSEQ + (size_t)c * QCHUNK;
    const bf16* xg = x + row0 * DINNER + h * HEADDIM;
    const bf16* Bg = zb + row0 * ZDIM + DINNER + h * DSTATE;

    const int t = tid >> 2, dseg = (tid & 3) * 32, sseg = (tid & 3) * 16;
    bf16x8 xr[4], br[2];
#pragma unroll
    for (int q = 0; q < 4; q++)
        xr[q] = *reinterpret_cast<const bf16x8*>(xg + (size_t)t * DINNER + dseg + q * 8);
#pragma unroll
    for (int q = 0; q < 2; q++)
        br[q] = *reinterpret_cast<const bf16x8*>(Bg + (size_t)t * ZDIM + sseg + q * 8);

    if (w == 0) {
        float v = la[(row0 + lane) * NHEADS + h];
#pragma unroll
        for (int off = 1; off < 64; off <<= 1) { float o = __shfl_up(v, off); if (lane >= off) v += o; }
        Ls[lane] = v;
        if (lane == 63) Adec[((size_t)b * NHEADS + h) * NCHUNK + c] = __expf(v);
    }
    __syncthreads();
    const float wt = __expf(Ls[QCHUNK - 1] - Ls[t]);
    const int tb = t >> 3, ti = t & 7;
#pragma unroll
    for (int q = 0; q < 4; q++)
#pragma unroll
        for (int j = 0; j < 8; j++) {
            int d = dseg + q * 8 + j;
            xt[d * 64 + ((tb ^ (d & 7)) << 3) + ti] = xr[q][j];
        }
#pragma unroll
    for (int q = 0; q < 2; q++)
#pragma unroll
        for (int j = 0; j < 8; j++) {
            int s = sseg + q * 8 + j;
            bw[s * 64 + ((tb ^ (s & 7)) << 3) + ti] = (bf16)((float)br[q][j] * wt);
        }
    __syncthreads();

    f32x4 acc[2][4];
#pragma unroll
    for (int i = 0; i < 2; i++)
#pragma unroll
        for (int j = 0; j < 4; j++) acc[i][j] = (f32x4){0.f, 0.f, 0.f, 0.f};
#pragma unroll
    for (int kk = 0; kk < 2; kk++) {
        const int kb = kk * 4 + (lane >> 4);
        bf16x8 af[2], bf2[4];
#pragma unroll
        for (int i = 0; i < 2; i++) {
            int d = w * 32 + i * 16 + (lane & 15);
            af[i] = *reinterpret_cast<const bf16x8*>(&xt[d * 64 + ((kb ^ (d & 7)) << 3)]);
        }
#pragma unroll
        for (int j = 0; j < 4; j++) {
            int s = j * 16 + (lane & 15);
            bf2[j] = *reinterpret_cast<const bf16x8*>(&bw[s * 64 + ((kb ^ (s & 7)) << 3)]);
        }
#pragma unroll
        for (int i = 0; i < 2; i++)
#pragma unroll
            for (int j = 0; j < 4; j++)
                acc[i][j] = __builtin_amdgcn_mfma_f32_16x16x32_bf16(af[i], bf2[j], acc[i][j], 0, 0, 0);
    }
    bf16* Sg = S + ((size_t)(b * NCHUNK + c) * NHEADS + h) * (HEADDIM * DSTATE);
    const int rr = (lane >> 4) * 4, ccol = lane & 15;
#pragma unroll
    for (int i = 0; i < 2; i++)
#pragma unroll
        for (int j = 0; j < 4; j++)
#pragma unroll
            for (int r = 0; r < 4; r++)
                Sg[(w * 32 + i * 16 + rr + r) * 64 + j * 16 + ccol] = (bf16)acc[i][j][r];
}

// Pass 1b: inter-chunk carry, in-place: S_c -> H_c (state at chunk START).
__global__ void chunk_carry_kernel(bf16* S, const float* __restrict__ A)
{
    int gid = blockIdx.x * 256 + threadIdx.x;
    if (gid >= BATCH * NHEADS * HEADDIM * DSTATE) return;
    int es = gid & (HEADDIM * DSTATE - 1);
    int h  = (gid >> 13) & (NHEADS - 1);
    int b  = gid >> 17;
    const float* Ab = A + ((size_t)b * NHEADS + h) * NCHUNK;
    float hstate = 0.f;
    size_t stride = (size_t)NHEADS * HEADDIM * DSTATE;
    bf16* p = S + ((size_t)b * NCHUNK * NHEADS + h) * (HEADDIM * DSTATE) + es;
    for (int c = 0; c < NCHUNK; ++c) {
        float sv = (float)*p;
        *p = (bf16)hstate;
        hstate = fmaf(Ab[c], hstate, sv);
        p += stride;
    }
}

// Pass 2: Y^T[d][t] = [Xt | H] @ [MG | P.C]^T  (K = 64 t' + 64 s), in-place over X.
__global__ __launch_bounds__(256) void chunk_y_kernel(
    bf16* xy,                       // [BL][DINNER]: x in, y out (same storage)
    const bf16* __restrict__ zb,    // B/C in z, stride ZDIM
    const float* __restrict__ la,   // [BL][16] log a
    const bf16* __restrict__ H)     // [B][NCHUNK][NHEADS][128*64] chunk-start state
{
    __shared__ __align__(16) bf16 bc[QCHUNK * 128];    // B | C, later MG[64][128]
    __shared__ __align__(16) bf16 xt[HEADDIM * QCHUNK];
    __shared__ __align__(16) bf16 hl[HEADDIM * DSTATE];
    __shared__ float Ls[QCHUNK];
    const int blk = blockIdx.x;
    const int h = blk & 15, c = (blk >> 4) & 63, b = blk >> 10;
    const int tid = threadIdx.x, lane = tid & 63, w = tid >> 6;
    const size_t row0 = (size_t)b * LSEQ + (size_t)c * QCHUNK;
    bf16* xg = xy + row0 * DINNER + h * HEADDIM;
    const bf16* Bg = zb + row0 * ZDIM + DINNER + h * DSTATE;
    const bf16* Cg = Bg + NHEADS * DSTATE;
    const bf16* Hg = H + ((size_t)(b * NCHUNK + c) * NHEADS + h) * (HEADDIM * DSTATE);

#pragma unroll
    for (int it = 0; it < 2; it++) {
        int idx = it * 256 + tid;
        int row = idx >> 3, p = idx & 7;
        int sc = (p ^ (row & 7)) << 3;
        __builtin_amdgcn_global_load_lds((const AS1 void*)(Bg + (size_t)row * ZDIM + sc),
                                         (AS3 void*)(&bc[idx * 8]), 16, 0, 0);
        __builtin_amdgcn_global_load_lds((const AS1 void*)(Cg + (size_t)row * ZDIM + sc),
                                         (AS3 void*)(&bc[4096 + idx * 8]), 16, 0, 0);
    }
#pragma unroll
    for (int it = 0; it < 4; it++) {
        int idx = it * 256 + tid;
        int d = idx >> 3, p = idx & 7;
        __builtin_amdgcn_global_load_lds((const AS1 void*)(Hg + d * 64 + ((p ^ (d & 7)) << 3)),
                                         (AS3 void*)(&hl[idx * 8]), 16, 0, 0);
    }
    const int t = tid >> 2, dseg = (tid & 3) * 32, sseg = (tid & 3) * 16;
    bf16x8 xr[4];
#pragma unroll
    for (int q = 0; q < 4; q++)
        xr[q] = *reinterpret_cast<const bf16x8*>(xg + (size_t)t * DINNER + dseg + q * 8);
    if (w == 0) {
        float v = la[(row0 + lane) * NHEADS + h];
#pragma unroll
        for (int off = 1; off < 64; off <<= 1) { float o = __shfl_up(v, off); if (lane >= off) v += o; }
        Ls[lane] = v;
    }
    __syncthreads();

    const int tb = t >> 3, ti = t & 7;
#pragma unroll
    for (int q = 0; q < 4; q++)
#pragma unroll
        for (int j = 0; j < 8; j++) {
            int d = dseg + q * 8 + j;
            xt[d * 64 + ((tb ^ (d & 7)) << 3) + ti] = xr[q][j];
        }

    f32x4 g[4];
#pragma unroll
    for (int j = 0; j < 4; j++) g[j] = (f32x4){0.f, 0.f, 0.f, 0.f};
#pragma unroll
    for (int kk = 0; kk < 2; kk++) {
        const int kb = kk * 4 + (lane >> 4);
        const int tA = w * 16 + (lane & 15);
        bf16x8 ca = *reinterpret_cast<const bf16x8*>(&bc[4096 + tA * 64 + ((kb ^ (tA & 7)) << 3)]);
#pragma unroll
        for (int j = 0; j < 4; j++) {
            int tB = j * 16 + (lane & 15);
            bf16x8 bb = *reinterpret_cast<const bf16x8*>(&bc[tB * 64 + ((kb ^ (tB & 7)) << 3)]);
            g[j] = __builtin_amdgcn_mfma_f32_16x16x32_bf16(ca, bb, g[j], 0, 0, 0);
        }
    }
    bf16x8 cr[2];
#pragma unroll
    for (int q = 0; q < 2; q++) {
        int sblk = (sseg >> 3) + q;
        cr[q] = *reinterpret_cast<const bf16x8*>(&bc[4096 + t * 64 + ((sblk ^ (t & 7)) << 3)]);
    }
    const float pscale = __expf(Ls[t]);
    __syncthreads();

    {
        const int tpbase = lane & 15;
        const int tgbase = w * 16 + (lane >> 4) * 4;
        float lst[4];
#pragma unroll
        for (int r = 0; r < 4; r++) lst[r] = Ls[tgbase + r];
#pragma unroll
        for (int j = 0; j < 4; j++) {
            int tp = j * 16 + tpbase;
            float lstp = Ls[tp];
#pragma unroll
            for (int r = 0; r < 4; r++) {
                int tg = tgbase + r;
                float mg = (tp <= tg) ? g[j][r] * __expf(lst[r] - lstp) : 0.f;
                bc[tg * 128 + (((tp >> 3) ^ (tg & 7)) << 3) + (tp & 7)] = (bf16)mg;
            }
        }
    }
#pragma unroll
    for (int q = 0; q < 2; q++) {
        int sblk = (sseg >> 3) + q;
        bf16x8 o;
#pragma unroll
        for (int j = 0; j < 8; j++) o[j] = (bf16)((float)cr[q][j] * pscale);
        *reinterpret_cast<bf16x8*>(&bc[t * 128 + ((8 + (sblk ^ (t & 7))) << 3)]) = o;
    }
    __syncthreads();

    f32x4 acc[2][4];
#pragma unroll
    for (int i = 0; i < 2; i++)
#pragma unroll
        for (int j = 0; j < 4; j++) acc[i][j] = (f32x4){0.f, 0.f, 0.f, 0.f};
#pragma unroll
    for (int kk = 0; kk < 4; kk++) {
        const int kb = kk * 4 + (lane >> 4);
        bf16x8 af[2];
#pragma unroll
        for (int i = 0; i < 2; i++) {
            int d = w * 32 + i * 16 + (lane & 15);
            if (kk < 2)
                af[i] = *reinterpret_cast<const bf16x8*>(&xt[d * 64 + ((kb ^ (d & 7)) << 3)]);
            else
                af[i] = *reinterpret_cast<const bf16x8*>(&hl[d * 64 + (((kb - 8) ^ (d & 7)) << 3)]);
        }
#pragma unroll
        for (int j = 0; j < 4; j++) {
            int tt = j * 16 + (lane & 15);
            bf16x8 b2 = *reinterpret_cast<const bf16x8*>(&bc[tt * 128 + ((kb ^ (tt & 7)) << 3)]);
#pragma unroll
            for (int i = 0; i < 2; i++)
                acc[i][j] = __builtin_amdgcn_mfma_f32_16x16x32_bf16(af[i], b2, acc[i][j], 0, 0, 0);
        }
    }
#pragma unroll
    for (int i = 0; i < 2; i++)
#pragma unroll
        for (int j = 0; j < 4; j++) {
            int d0 = w * 32 + i * 16 + (lane >> 4) * 4;
            int tt = j * 16 + (lane & 15);
            bf16x4 o;
#pragma unroll
            for (int r = 0; r < 4; r++) o[r] = (bf16)acc[i][j][r];
            *reinterpret_cast<bf16x4*>(xg + (size_t)tt * DINNER + d0) = o;
        }
}

// ---------------- gate (sigmoid) * y, RMS norm, -> bf16 (in-place over g) ----------------
__global__ __launch_bounds__(256) void gate_rms_kernel(
    const bf16* __restrict__ y,   // [BL][2048]
    bf16* g,                      // [BL][2048]: gate pre-act in, normalized y out
    const float* __restrict__ norm_w)
{
    __shared__ float red[4];
    int row = blockIdx.x, t = threadIdx.x;
    const bf16* yr = y + (size_t)row * DINNER;
    bf16* gr = g + (size_t)row * DINNER;
    int c0 = t * 8;
    bf16x8 yv8 = *reinterpret_cast<const bf16x8*>(yr + c0);
    bf16x8 gv8 = *reinterpret_cast<const bf16x8*>(gr + c0);
    float v[8];
#pragma unroll
    for (int i = 0; i < 8; i++) {
        float yf = (float)yv8[i];
        float gf = (float)gv8[i];
        v[i] = yf / (1.f + expf(-gf));
    }
    float ss = 0.f;
#pragma unroll
    for (int i = 0; i < 8; i++) ss += v[i] * v[i];
#pragma unroll
    for (int off = 32; off >= 1; off >>= 1) ss += __shfl_xor(ss, off);
    if ((t & 63) == 0) red[t >> 6] = ss;
    __syncthreads();
    ss = red[0] + red[1] + red[2] + red[3];
    float sc = rsqrtf(ss * (1.0f / DINNER) + 1.1920928955078125e-07f);
    float4 na = *reinterpret_cast<const float4*>(norm_w + c0);
    float4 nb = *reinterpret_cast<const float4*>(norm_w + c0 + 4);
    bf16x8 ov;
    ov[0] = (bf16)(v[0] * sc * na.x);
    ov[1] = (bf16)(v[1] * sc * na.y);
    ov[2] = (bf16)(v[2] * sc * na.z);
    ov[3] = (bf16)(v[3] * sc * na.w);
    ov[4] = (bf16)(v[4] * sc * nb.x);
    ov[5] = (bf16)(v[5] * sc * nb.y);
    ov[6] = (bf16)(v[6] * sc * nb.z);
    ov[7] = (bf16)(v[7] * sc * nb.w);
    *reinterpret_cast<bf16x8*>(gr + c0) = ov;
}

// ---------------- launch ----------------
extern "C" void kernel_launch(void* const* d_in, const int* in_sizes, int n_in,
                              void* d_out, int out_size, void* d_ws, size_t ws_size,
                              hipStream_t stream)
{
    const float* u      = (const float*)d_in[0];
    const float* W_in   = (const float*)d_in[1];
    const float* conv_w = (const float*)d_in[2];
    const float* conv_b = (const float*)d_in[3];
    const float* dparam = (const float*)d_in[4];
    const float* W_gate = (const float*)d_in[5];
    const float* norm_w = (const float*)d_in[6];
    const float* W_out  = (const float*)d_in[7];
    float* out = (float*)d_out;

    char* ws = (char*)d_ws;
    size_t off = 0;
    auto alloc = [&](size_t bytes) {
        void* p = ws + off;
        off += (bytes + 255) & ~(size_t)255;
        return p;
    };
    // total ws use: ~170 MB
    bf16*  u_bf  = (bf16*) alloc((size_t)BLROWS * DMODEL * 2);   // 16.8 MB
    bf16*  Wt_f  = (bf16*) alloc((size_t)NFUSE * DMODEL * 2);    // 13.1 MB (W_in | pad | W_gate | pad)
    bf16*  Wt_o  = (bf16*) alloc((size_t)DMODEL * DINNER * 2);   // 4.2 MB
    bf16*  z     = (bf16*) alloc((size_t)BLROWS * ZDIM * 2);     // 67.4 MB
    bf16*  g     = (bf16*) alloc((size_t)BLROWS * DINNER * 2);   // 33.6 MB (yn in-place)
    float* dt    = (float*)alloc((size_t)BLROWS * NHEADS * 4);   // 0.5 MB
    float* lab   = (float*)alloc((size_t)BLROWS * NHEADS * 4);   // 0.5 MB (log a)
    bf16*  S     = (bf16*) alloc((size_t)BATCH * NCHUNK * NHEADS * HEADDIM * DSTATE * 2); // 33.6 MB
    float* Adec  = (float*)alloc((size_t)BATCH * NHEADS * NCHUNK * 4);                    // 8 KB
    bf16* xy = (bf16*)d_out;   // x/y live in d_out, fully overwritten by final GEMM
    (void)ws_size; (void)in_sizes; (void)n_in; (void)out_size;

    dim3 tb(32, 8);
    cvt_bf16_kernel<<<(BLROWS * DMODEL / 4 + 255) / 256, 256, 0, stream>>>(u, u_bf, BLROWS * DMODEL);
    // fused weight: rows 0..4111 = W_in^T, 4112..4223 = 0, 4224..6271 = W_gate^T, 6272..6399 = 0
    transpose_cvt_kernel<<<dim3(4224 / 32, DMODEL / 32), tb, 0, stream>>>(W_in, Wt_f, DMODEL, ZDIM, 4224);
    transpose_cvt_kernel<<<dim3(2176 / 32, DMODEL / 32), tb, 0, stream>>>(W_gate, Wt_f + (size_t)4224 * DMODEL, DMODEL, DINNER, 2176);
    transpose_cvt_kernel<<<dim3(DMODEL / 32, DINNER / 32), tb, 0, stream>>>(W_out, Wt_o, DINNER, DMODEL, DMODEL);

    // fused z|g GEMM: M=8192, K=1024 (32 slices), N=6400, grid 800 (800%8==0)
    gemm8p_kernel<32, 1024, 0, 256, 25><<<(BLROWS / 256) * (NFUSE / 256), 512, 0, stream>>>(
        u_bf, Wt_f, z, g, dt, nullptr);

    conv_silu_kernel<<<(BLROWS * (DINNER / 8) + 255) / 256, 256, 0, stream>>>(z, conv_w, conv_b, xy);
    la_kernel<<<(BLROWS * NHEADS + 255) / 256, 256, 0, stream>>>(dt, dparam, lab);

    // chunked scan (SSD matmul form)
    chunk_state_kernel<<<BATCH * NCHUNK * NHEADS, 256, 0, stream>>>(xy, z, lab, S, Adec);
    chunk_carry_kernel<<<(BATCH * NHEADS * HEADDIM * DSTATE) / 256, 256, 0, stream>>>(S, Adec);
    chunk_y_kernel<<<BATCH * NCHUNK * NHEADS, 256, 0, stream>>>(xy, z, lab, S);

    gate_rms_kernel<<<BLROWS, 256, 0, stream>>>(xy, g, norm_w);

    // out = yn @ W_out (f32 out): M=8192, K=2048 (64 slices), N=1024, BN=128, grid 256
    gemm8p_kernel<64, 2048, 1, 128, 8><<<(BLROWS / 256) * (1024 / 128), 512, 0, stream>>>(
        g, Wt_o, nullptr, nullptr, nullptr, out);
}

// Round 11
// 360.597 us; speedup vs baseline: 3.9534x; 3.9534x over previous
//
#include <hip/hip_runtime.h>

#define BATCH   2
#define LSEQ    4096
#define DMODEL  1024
#define DINNER  2048
#define NHEADS  16
#define DSTATE  64
#define HEADDIM 128
#define ZDIM    4112
#define BLROWS  (BATCH*LSEQ)   // 8192
#define NFUSE   6400           // 4112(z)+112(pad)+2048(g)+128(pad), 50*128
#define QCHUNK  64
#define NCHUNK  (LSEQ/QCHUNK)  // 64

#define AS1 __attribute__((address_space(1)))
#define AS3 __attribute__((address_space(3)))

typedef __bf16 bf16;
typedef __bf16 bf16x8 __attribute__((ext_vector_type(8)));
typedef __bf16 bf16x4 __attribute__((ext_vector_type(4)));
typedef float  f32x4  __attribute__((ext_vector_type(4)));

// paired-row LDS swizzle for [R rows][32 bf16] regions: logical (row, 16B-chunk c) ->
// element offset. Read of 16 consecutive rows at fixed c hits all banks x2 = free.
__device__ __forceinline__ int lds_elem(int row, int c)
{
    return (row >> 1) * 64 + (row & 1) * 32 + (((c ^ ((row >> 1) & 3)) & 3) << 3);
}

// ---------------- fp32 -> bf16 convert (vectorized) ----------------
__global__ void cvt_bf16_kernel(const float* __restrict__ in, bf16* __restrict__ out, int n)
{
    int i = (blockIdx.x * 256 + threadIdx.x) * 4;
    if (i >= n) return;
    float4 v = *reinterpret_cast<const float4*>(in + i);
    bf16x4 o;
    o[0] = (bf16)v.x; o[1] = (bf16)v.y; o[2] = (bf16)v.z; o[3] = (bf16)v.w;
    *reinterpret_cast<bf16x4*>(out + i) = o;
}

// ---------------- transpose + convert: src[R][C] f32 -> dst[Cpad][R] bf16 ----------------
__global__ void transpose_cvt_kernel(const float* __restrict__ src, bf16* __restrict__ dst,
                                     int R, int C, int Cpad)
{
    __shared__ float tile[32][33];
    int tx = threadIdx.x;   // 0..31
    int ty = threadIdx.y;   // 0..7
    int c0 = blockIdx.x * 32;
    int r0 = blockIdx.y * 32;
#pragma unroll
    for (int q = 0; q < 4; q++) {
        int r = r0 + ty + q * 8;
        int c = c0 + tx;
        float v = 0.f;
        if (r < R && c < C) v = src[(size_t)r * C + c];
        tile[ty + q * 8][tx] = v;
    }
    __syncthreads();
#pragma unroll
    for (int q = 0; q < 4; q++) {
        int oc = c0 + ty + q * 8;   // output row (= original col)
        int orr = r0 + tx;          // output col (= original row)
        if (oc < Cpad && orr < R)
            dst[(size_t)oc * R + orr] = (bf16)tile[tx][ty + q * 8];
    }
}

// ======= dbuf GEMM: 128x128 tile, 256 thr (4 waves 2x2), K-slices of 32, counted vmcnt =======
// XCD supertiling: xcd = bid&7 owns bm strip [xcd*8, xcd*8+8); bn sweeps bm-fast.
// Per phase: ds_read(slot p) ; lgkm(0) ; barrier [slot p dead] ; STAGE(p+2 -> slot p) ;
// MFMA ; vmcnt(4) [slot p+1 landed, stage p+2 in flight] ; barrier.
// 32KB LDS, ~120 VGPR -> 2-3 blocks/CU: co-resident blocks' MFMA covers LDS drains.
// MODE 0: fused z|g|dt epilogue.  MODE 1: f32 C[M][1024].
template<int NSLICE, int KROW, int MODE, int NBN>
__global__ __launch_bounds__(256) void gemm_db_kernel(
    const bf16* __restrict__ A, const bf16* __restrict__ Bt,
    bf16* __restrict__ z, bf16* __restrict__ g, float* __restrict__ dtout,
    float* __restrict__ c32)
{
    constexpr int SLOTSZ = 256 * 32;         // bf16 per slot (A 128x32 | B 128x32)
    __shared__ __align__(16) bf16 lds[2 * SLOTSZ];   // 32 KB
    const int tid = threadIdx.x;
    const int lane = tid & 63, wid = tid >> 6;
    const int wm = (wid >> 1) * 64, wn = (wid & 1) * 64;
    const int lml = lane & 15, kc = lane >> 4;

    // XCD supertile map: grid = 64*NBN (divisible by 8). Each XCD: 8 bm x NBN bn, bm-fast.
    const int bid = blockIdx.x;
    const int xcd = bid & 7;
    const int idx = bid >> 3;
    const int bm = xcd * 8 + (idx & 7);
    const int bn = idx >> 3;

    const bf16* Abase = A + (size_t)(bm * 128) * KROW;
    const bf16* Bbase = Bt + (size_t)(bn * 128) * KROW;

#define STAGE8(pp) do {                                                                  \
    const int _p = (pp); const int _slot = _p & 1; const size_t _ko = (size_t)_p * 32;   \
    _Pragma("unroll") for (int it = 0; it < 4; ++it) {                                   \
        int q = it * 256 + tid;           /* 0..1023: 512 A-chunks then 512 B-chunks */  \
        int o = (q < 512) ? q : q - 512;                                                 \
        int prow = o >> 3, wi = o & 7;                                                   \
        int row = prow * 2 + (wi >> 2), c = (wi & 3) ^ (prow & 3);                       \
        const bf16* _src = ((q < 512) ? Abase : Bbase) + (size_t)row * KROW + _ko + c * 8; \
        int _dst = _slot * SLOTSZ + ((q < 512) ? 0 : 4096) + o * 8;                      \
        __builtin_amdgcn_global_load_lds((const AS1 void*)_src,                          \
            (AS3 void*)(&lds[_dst]), 16, 0, 0);                                          \
    }                                                                                    \
} while (0)

    f32x4 acc[4][4];
#pragma unroll
    for (int i = 0; i < 4; i++)
#pragma unroll
        for (int j = 0; j < 4; j++) acc[i][j] = (f32x4){0.f, 0.f, 0.f, 0.f};

    STAGE8(0); STAGE8(1);
    asm volatile("s_waitcnt vmcnt(4)" ::: "memory");   // slot 0 landed (slot 1 in flight)
    __builtin_amdgcn_s_barrier();

    for (int p = 0; p < NSLICE; ++p) {
        const bf16* base_ = &lds[(p & 1) * SLOTSZ];
        bf16x8 af[4], bfv[4];
#pragma unroll
        for (int i = 0; i < 4; ++i) {
            int row = wm + i * 16 + lml;
            af[i] = *reinterpret_cast<const bf16x8*>(&base_[lds_elem(row, kc)]);
        }
#pragma unroll
        for (int j = 0; j < 4; ++j) {
            int row = wn + j * 16 + lml;
            bfv[j] = *reinterpret_cast<const bf16x8*>(&base_[4096 + lds_elem(row, kc)]);
        }
        asm volatile("s_waitcnt lgkmcnt(0)" ::: "memory");
        __builtin_amdgcn_sched_barrier(0);
        __builtin_amdgcn_s_barrier();        // slot p fully consumed by all waves
        if (p + 2 < NSLICE) STAGE8(p + 2);   // overwrite slot p&1
        __builtin_amdgcn_sched_barrier(0);
        __builtin_amdgcn_s_setprio(1);
#pragma unroll
        for (int i = 0; i < 4; ++i)
#pragma unroll
            for (int j = 0; j < 4; ++j)
                acc[i][j] = __builtin_amdgcn_mfma_f32_16x16x32_bf16(af[i], bfv[j], acc[i][j], 0, 0, 0);
        __builtin_amdgcn_s_setprio(0);
        if (p + 1 < NSLICE) {
            if (p + 2 < NSLICE) { asm volatile("s_waitcnt vmcnt(4)" ::: "memory"); }
            else { asm volatile("s_waitcnt vmcnt(0)" ::: "memory"); }
            __builtin_amdgcn_s_barrier();
        }
    }
#undef STAGE8

    const int rbase = (lane >> 4) * 4;
#pragma unroll
    for (int i = 0; i < 4; i++) {
#pragma unroll
        for (int j = 0; j < 4; j++) {
            int col = bn * 128 + wn + j * 16 + lml;
            if constexpr (MODE == 0) {
                bool isZ = (col < ZDIM);
                bool isG = (col >= 4224) && (col < 4224 + DINNER);
                bool isDT = (col >= 4096) && (col < ZDIM);
                if (!isZ && !isG) continue;
#pragma unroll
                for (int r = 0; r < 4; r++) {
                    int row = bm * 128 + wm + i * 16 + rbase + r;
                    float v = acc[i][j][r];
                    if (isZ) {
                        z[(size_t)row * ZDIM + col] = (bf16)v;
                        if (isDT) dtout[(size_t)row * NHEADS + (col - 4096)] = v;
                    } else {
                        g[(size_t)row * DINNER + (col - 4224)] = (bf16)v;
                    }
                }
            } else {
#pragma unroll
                for (int r = 0; r < 4; r++) {
                    int row = bm * 128 + wm + i * 16 + rbase + r;
                    c32[(size_t)row * 1024 + col] = acc[i][j][r];
                }
            }
        }
    }
}

// ---------------- causal depthwise conv (D_CONV=4) + SiLU, bf16x8 vectorized ----------------
__global__ void conv_silu_kernel(const bf16* __restrict__ z, const float* __restrict__ conv_w,
                                 const float* __restrict__ conv_b, bf16* __restrict__ x)
{
    int gid = blockIdx.x * 256 + threadIdx.x;   // one thread per 8 channels
    if (gid >= BLROWS * (DINNER / 8)) return;
    int c0 = (gid & 255) * 8;
    int bl = gid >> 8;
    int l = bl & (LSEQ - 1);
    float4 wv[8];
#pragma unroll
    for (int e = 0; e < 8; e++) wv[e] = *reinterpret_cast<const float4*>(conv_w + (size_t)(c0 + e) * 4);
    float a8[8];
    {
        float4 b0 = *reinterpret_cast<const float4*>(conv_b + c0);
        float4 b1 = *reinterpret_cast<const float4*>(conv_b + c0 + 4);
        a8[0] = b0.x; a8[1] = b0.y; a8[2] = b0.z; a8[3] = b0.w;
        a8[4] = b1.x; a8[5] = b1.y; a8[6] = b1.z; a8[7] = b1.w;
    }
#pragma unroll
    for (int k = 0; k < 4; k++) {
        if (l - 3 + k >= 0) {
            bf16x8 zv = *reinterpret_cast<const bf16x8*>(z + (size_t)(bl - 3 + k) * ZDIM + c0);
            const float* wk;
#pragma unroll
            for (int e = 0; e < 8; e++) {
                wk = reinterpret_cast<const float*>(&wv[e]);
                a8[e] = fmaf((float)zv[e], wk[k], a8[e]);
            }
        }
    }
    bf16x8 o;
#pragma unroll
    for (int e = 0; e < 8; e++) o[e] = (bf16)(a8[e] / (1.f + expf(-a8[e])));
    *reinterpret_cast<bf16x8*>(x + (size_t)bl * DINNER + c0) = o;
}

// ---------------- la = log(a_bar) = -softplus(dt+dp)*|dt| ----------------
__global__ void la_kernel(const float* __restrict__ dt_in, const float* __restrict__ dparam,
                          float* __restrict__ la)
{
    int i = blockIdx.x * 256 + threadIdx.x;
    if (i >= BLROWS * NHEADS) return;
    int h = i & (NHEADS - 1);
    float dt = dt_in[i];
    float v = dt + dparam[h];
    float sp = (v > 20.f) ? v : log1pf(expf(v));
    la[i] = -sp * fabsf(dt);
}

// ================= chunked scan, SSD matmul form =================
__global__ __launch_bounds__(256) void chunk_state_kernel(
    const bf16* __restrict__ x,    // [BL][DINNER]
    const bf16* __restrict__ zb,   // B at col DINNER+h*64, stride ZDIM
    const float* __restrict__ la,  // [BL][16] log a
    bf16* __restrict__ S,          // [B][NCHUNK][NHEADS][128*64]
    float* __restrict__ Adec)      // [B][NHEADS][NCHUNK] = exp(Ls_Q)
{
    __shared__ __align__(16) bf16 xt[HEADDIM * QCHUNK]; // [d][t] swizzled
    __shared__ __align__(16) bf16 bw[DSTATE * QCHUNK];  // [s][t] swizzled, weighted
    __shared__ float Ls[QCHUNK];
    const int blk = blockIdx.x;
    const int h = blk & 15, c = (blk >> 4) & 63, b = blk >> 10;
    const int tid = threadIdx.x, lane = tid & 63, w = tid >> 6;
    const size_t row0 = (size_t)b * LSEQ + (size_t)c * QCHUNK;
    const bf16* xg = x + row0 * DINNER + h * HEADDIM;
    const bf16* Bg = zb + row0 * ZDIM + DINNER + h * DSTATE;

    const int t = tid >> 2, dseg = (tid & 3) * 32, sseg = (tid & 3) * 16;
    bf16x8 xr[4], br[2];
#pragma unroll
    for (int q = 0; q < 4; q++)
        xr[q] = *reinterpret_cast<const bf16x8*>(xg + (size_t)t * DINNER + dseg + q * 8);
#pragma unroll
    for (int q = 0; q < 2; q++)
        br[q] = *reinterpret_cast<const bf16x8*>(Bg + (size_t)t * ZDIM + sseg + q * 8);

    if (w == 0) {
        float v = la[(row0 + lane) * NHEADS + h];
#pragma unroll
        for (int off = 1; off < 64; off <<= 1) { float o = __shfl_up(v, off); if (lane >= off) v += o; }
        Ls[lane] = v;
        if (lane == 63) Adec[((size_t)b * NHEADS + h) * NCHUNK + c] = __expf(v);
    }
    __syncthreads();
    const float wt = __expf(Ls[QCHUNK - 1] - Ls[t]);
    const int tb = t >> 3, ti = t & 7;
#pragma unroll
    for (int q = 0; q < 4; q++)
#pragma unroll
        for (int j = 0; j < 8; j++) {
            int d = dseg + q * 8 + j;
            xt[d * 64 + ((tb ^ (d & 7)) << 3) + ti] = xr[q][j];
        }
#pragma unroll
    for (int q = 0; q < 2; q++)
#pragma unroll
        for (int j = 0; j < 8; j++) {
            int s = sseg + q * 8 + j;
            bw[s * 64 + ((tb ^ (s & 7)) << 3) + ti] = (bf16)((float)br[q][j] * wt);
        }
    __syncthreads();

    f32x4 acc[2][4];
#pragma unroll
    for (int i = 0; i < 2; i++)
#pragma unroll
        for (int j = 0; j < 4; j++) acc[i][j] = (f32x4){0.f, 0.f, 0.f, 0.f};
#pragma unroll
    for (int kk = 0; kk < 2; kk++) {
        const int kb = kk * 4 + (lane >> 4);
        bf16x8 af[2], bf2[4];
#pragma unroll
        for (int i = 0; i < 2; i++) {
            int d = w * 32 + i * 16 + (lane & 15);
            af[i] = *reinterpret_cast<const bf16x8*>(&xt[d * 64 + ((kb ^ (d & 7)) << 3)]);
        }
#pragma unroll
        for (int j = 0; j < 4; j++) {
            int s = j * 16 + (lane & 15);
            bf2[j] = *reinterpret_cast<const bf16x8*>(&bw[s * 64 + ((kb ^ (s & 7)) << 3)]);
        }
#pragma unroll
        for (int i = 0; i < 2; i++)
#pragma unroll
            for (int j = 0; j < 4; j++)
                acc[i][j] = __builtin_amdgcn_mfma_f32_16x16x32_bf16(af[i], bf2[j], acc[i][j], 0, 0, 0);
    }
    bf16* Sg = S + ((size_t)(b * NCHUNK + c) * NHEADS + h) * (HEADDIM * DSTATE);
    const int rr = (lane >> 4) * 4, ccol = lane & 15;
#pragma unroll
    for (int i = 0; i < 2; i++)
#pragma unroll
        for (int j = 0; j < 4; j++)
#pragma unroll
            for (int r = 0; r < 4; r++)
                Sg[(w * 32 + i * 16 + rr + r) * 64 + j * 16 + ccol] = (bf16)acc[i][j][r];
}

// Pass 1b: inter-chunk carry, in-place: S_c -> H_c (state at chunk START).
__global__ void chunk_carry_kernel(bf16* S, const float* __restrict__ A)
{
    int gid = blockIdx.x * 256 + threadIdx.x;
    if (gid >= BATCH * NHEADS * HEADDIM * DSTATE) return;
    int es = gid & (HEADDIM * DSTATE - 1);
    int h  = (gid >> 13) & (NHEADS - 1);
    int b  = gid >> 17;
    const float* Ab = A + ((size_t)b * NHEADS + h) * NCHUNK;
    float hstate = 0.f;
    size_t stride = (size_t)NHEADS * HEADDIM * DSTATE;
    bf16* p = S + ((size_t)b * NCHUNK * NHEADS + h) * (HEADDIM * DSTATE) + es;
    for (int c = 0; c < NCHUNK; ++c) {
        float sv = (float)*p;
        *p = (bf16)hstate;
        hstate = fmaf(Ab[c], hstate, sv);
        p += stride;
    }
}

// Pass 2: Y^T[d][t] = [Xt | H] @ [MG | P.C]^T  (K = 64 t' + 64 s), in-place over X.
__global__ __launch_bounds__(256) void chunk_y_kernel(
    bf16* xy,                       // [BL][DINNER]: x in, y out (same storage)
    const bf16* __restrict__ zb,    // B/C in z, stride ZDIM
    const float* __restrict__ la,   // [BL][16] log a
    const bf16* __restrict__ H)     // [B][NCHUNK][NHEADS][128*64] chunk-start state
{
    __shared__ __align__(16) bf16 bc[QCHUNK * 128];    // B | C, later MG[64][128]
    __shared__ __align__(16) bf16 xt[HEADDIM * QCHUNK];
    __shared__ __align__(16) bf16 hl[HEADDIM * DSTATE];
    __shared__ float Ls[QCHUNK];
    const int blk = blockIdx.x;
    const int h = blk & 15, c = (blk >> 4) & 63, b = blk >> 10;
    const int tid = threadIdx.x, lane = tid & 63, w = tid >> 6;
    const size_t row0 = (size_t)b * LSEQ + (size_t)c * QCHUNK;
    bf16* xg = xy + row0 * DINNER + h * HEADDIM;
    const bf16* Bg = zb + row0 * ZDIM + DINNER + h * DSTATE;
    const bf16* Cg = Bg + NHEADS * DSTATE;
    const bf16* Hg = H + ((size_t)(b * NCHUNK + c) * NHEADS + h) * (HEADDIM * DSTATE);

#pragma unroll
    for (int it = 0; it < 2; it++) {
        int idx = it * 256 + tid;
        int row = idx >> 3, p = idx & 7;
        int sc = (p ^ (row & 7)) << 3;
        __builtin_amdgcn_global_load_lds((const AS1 void*)(Bg + (size_t)row * ZDIM + sc),
                                         (AS3 void*)(&bc[idx * 8]), 16, 0, 0);
        __builtin_amdgcn_global_load_lds((const AS1 void*)(Cg + (size_t)row * ZDIM + sc),
                                         (AS3 void*)(&bc[4096 + idx * 8]), 16, 0, 0);
    }
#pragma unroll
    for (int it = 0; it < 4; it++) {
        int idx = it * 256 + tid;
        int d = idx >> 3, p = idx & 7;
        __builtin_amdgcn_global_load_lds((const AS1 void*)(Hg + d * 64 + ((p ^ (d & 7)) << 3)),
                                         (AS3 void*)(&hl[idx * 8]), 16, 0, 0);
    }
    const int t = tid >> 2, dseg = (tid & 3) * 32, sseg = (tid & 3) * 16;
    bf16x8 xr[4];
#pragma unroll
    for (int q = 0; q < 4; q++)
        xr[q] = *reinterpret_cast<const bf16x8*>(xg + (size_t)t * DINNER + dseg + q * 8);
    if (w == 0) {
        float v = la[(row0 + lane) * NHEADS + h];
#pragma unroll
        for (int off = 1; off < 64; off <<= 1) { float o = __shfl_up(v, off); if (lane >= off) v += o; }
        Ls[lane] = v;
    }
    __syncthreads();

    const int tb = t >> 3, ti = t & 7;
#pragma unroll
    for (int q = 0; q < 4; q++)
#pragma unroll
        for (int j = 0; j < 8; j++) {
            int d = dseg + q * 8 + j;
            xt[d * 64 + ((tb ^ (d & 7)) << 3) + ti] = xr[q][j];
        }

    f32x4 g[4];
#pragma unroll
    for (int j = 0; j < 4; j++) g[j] = (f32x4){0.f, 0.f, 0.f, 0.f};
#pragma unroll
    for (int kk = 0; kk < 2; kk++) {
        const int kb = kk * 4 + (lane >> 4);
        const int tA = w * 16 + (lane & 15);
        bf16x8 ca = *reinterpret_cast<const bf16x8*>(&bc[4096 + tA * 64 + ((kb ^ (tA & 7)) << 3)]);
#pragma unroll
        for (int j = 0; j < 4; j++) {
            int tB = j * 16 + (lane & 15);
            bf16x8 bb = *reinterpret_cast<const bf16x8*>(&bc[tB * 64 + ((kb ^ (tB & 7)) << 3)]);
            g[j] = __builtin_amdgcn_mfma_f32_16x16x32_bf16(ca, bb, g[j], 0, 0, 0);
        }
    }
    bf16x8 cr[2];
#pragma unroll
    for (int q = 0; q < 2; q++) {
        int sblk = (sseg >> 3) + q;
        cr[q] = *reinterpret_cast<const bf16x8*>(&bc[4096 + t * 64 + ((sblk ^ (t & 7)) << 3)]);
    }
    const float pscale = __expf(Ls[t]);
    __syncthreads();

    {
        const int tpbase = lane & 15;
        const int tgbase = w * 16 + (lane >> 4) * 4;
        float lst[4];
#pragma unroll
        for (int r = 0; r < 4; r++) lst[r] = Ls[tgbase + r];
#pragma unroll
        for (int j = 0; j < 4; j++) {
            int tp = j * 16 + tpbase;
            float lstp = Ls[tp];
#pragma unroll
            for (int r = 0; r < 4; r++) {
                int tg = tgbase + r;
                float mg = (tp <= tg) ? g[j][r] * __expf(lst[r] - lstp) : 0.f;
                bc[tg * 128 + (((tp >> 3) ^ (tg & 7)) << 3) + (tp & 7)] = (bf16)mg;
            }
        }
    }
#pragma unroll
    for (int q = 0; q < 2; q++) {
        int sblk = (sseg >> 3) + q;
        bf16x8 o;
#pragma unroll
        for (int j = 0; j < 8; j++) o[j] = (bf16)((float)cr[q][j] * pscale);
        *reinterpret_cast<bf16x8*>(&bc[t * 128 + ((8 + (sblk ^ (t & 7))) << 3)]) = o;
    }
    __syncthreads();

    f32x4 acc[2][4];
#pragma unroll
    for (int i = 0; i < 2; i++)
#pragma unroll
        for (int j = 0; j < 4; j++) acc[i][j] = (f32x4){0.f, 0.f, 0.f, 0.f};
#pragma unroll
    for (int kk = 0; kk < 4; kk++) {
        const int kb = kk * 4 + (lane >> 4);
        bf16x8 af[2];
#pragma unroll
        for (int i = 0; i < 2; i++) {
            int d = w * 32 + i * 16 + (lane & 15);
            if (kk < 2)
                af[i] = *reinterpret_cast<const bf16x8*>(&xt[d * 64 + ((kb ^ (d & 7)) << 3)]);
            else
                af[i] = *reinterpret_cast<const bf16x8*>(&hl[d * 64 + (((kb - 8) ^ (d & 7)) << 3)]);
        }
#pragma unroll
        for (int j = 0; j < 4; j++) {
            int tt = j * 16 + (lane & 15);
            bf16x8 b2 = *reinterpret_cast<const bf16x8*>(&bc[tt * 128 + ((kb ^ (tt & 7)) << 3)]);
#pragma unroll
            for (int i = 0; i < 2; i++)
                acc[i][j] = __builtin_amdgcn_mfma_f32_16x16x32_bf16(af[i], b2, acc[i][j], 0, 0, 0);
        }
    }
#pragma unroll
    for (int i = 0; i < 2; i++)
#pragma unroll
        for (int j = 0; j < 4; j++) {
            int d0 = w * 32 + i * 16 + (lane >> 4) * 4;
            int tt = j * 16 + (lane & 15);
            bf16x4 o;
#pragma unroll
            for (int r = 0; r < 4; r++) o[r] = (bf16)acc[i][j][r];
            *reinterpret_cast<bf16x4*>(xg + (size_t)tt * DINNER + d0) = o;
        }
}

// ---------------- gate (sigmoid) * y, RMS norm, -> bf16 (in-place over g) ----------------
__global__ __launch_bounds__(256) void gate_rms_kernel(
    const bf16* __restrict__ y,   // [BL][2048]
    bf16* g,                      // [BL][2048]: gate pre-act in, normalized y out
    const float* __restrict__ norm_w)
{
    __shared__ float red[4];
    int row = blockIdx.x, t = threadIdx.x;
    const bf16* yr = y + (size_t)row * DINNER;
    bf16* gr = g + (size_t)row * DINNER;
    int c0 = t * 8;
    bf16x8 yv8 = *reinterpret_cast<const bf16x8*>(yr + c0);
    bf16x8 gv8 = *reinterpret_cast<const bf16x8*>(gr + c0);
    float v[8];
#pragma unroll
    for (int i = 0; i < 8; i++) {
        float yf = (float)yv8[i];
        float gf = (float)gv8[i];
        v[i] = yf / (1.f + expf(-gf));
    }
    float ss = 0.f;
#pragma unroll
    for (int i = 0; i < 8; i++) ss += v[i] * v[i];
#pragma unroll
    for (int off = 32; off >= 1; off >>= 1) ss += __shfl_xor(ss, off);
    if ((t & 63) == 0) red[t >> 6] = ss;
    __syncthreads();
    ss = red[0] + red[1] + red[2] + red[3];
    float sc = rsqrtf(ss * (1.0f / DINNER) + 1.1920928955078125e-07f);
    float4 na = *reinterpret_cast<const float4*>(norm_w + c0);
    float4 nb = *reinterpret_cast<const float4*>(norm_w + c0 + 4);
    bf16x8 ov;
    ov[0] = (bf16)(v[0] * sc * na.x);
    ov[1] = (bf16)(v[1] * sc * na.y);
    ov[2] = (bf16)(v[2] * sc * na.z);
    ov[3] = (bf16)(v[3] * sc * na.w);
    ov[4] = (bf16)(v[4] * sc * nb.x);
    ov[5] = (bf16)(v[5] * sc * nb.y);
    ov[6] = (bf16)(v[6] * sc * nb.z);
    ov[7] = (bf16)(v[7] * sc * nb.w);
    *reinterpret_cast<bf16x8*>(gr + c0) = ov;
}

// ---------------- launch ----------------
extern "C" void kernel_launch(void* const* d_in, const int* in_sizes, int n_in,
                              void* d_out, int out_size, void* d_ws, size_t ws_size,
                              hipStream_t stream)
{
    const float* u      = (const float*)d_in[0];
    const float* W_in   = (const float*)d_in[1];
    const float* conv_w = (const float*)d_in[2];
    const float* conv_b = (const float*)d_in[3];
    const float* dparam = (const float*)d_in[4];
    const float* W_gate = (const float*)d_in[5];
    const float* norm_w = (const float*)d_in[6];
    const float* W_out  = (const float*)d_in[7];
    float* out = (float*)d_out;

    char* ws = (char*)d_ws;
    size_t off = 0;
    auto alloc = [&](size_t bytes) {
        void* p = ws + off;
        off += (bytes + 255) & ~(size_t)255;
        return p;
    };
    // total ws use: ~170 MB
    bf16*  u_bf  = (bf16*) alloc((size_t)BLROWS * DMODEL * 2);   // 16.8 MB
    bf16*  Wt_f  = (bf16*) alloc((size_t)NFUSE * DMODEL * 2);    // 13.1 MB (W_in | pad | W_gate | pad)
    bf16*  Wt_o  = (bf16*) alloc((size_t)DMODEL * DINNER * 2);   // 4.2 MB
    bf16*  z     = (bf16*) alloc((size_t)BLROWS * ZDIM * 2);     // 67.4 MB
    bf16*  g     = (bf16*) alloc((size_t)BLROWS * DINNER * 2);   // 33.6 MB (yn in-place)
    float* dt    = (float*)alloc((size_t)BLROWS * NHEADS * 4);   // 0.5 MB
    float* lab   = (float*)alloc((size_t)BLROWS * NHEADS * 4);   // 0.5 MB (log a)
    bf16*  S     = (bf16*) alloc((size_t)BATCH * NCHUNK * NHEADS * HEADDIM * DSTATE * 2); // 33.6 MB
    float* Adec  = (float*)alloc((size_t)BATCH * NHEADS * NCHUNK * 4);                    // 8 KB
    bf16* xy = (bf16*)d_out;   // x/y live in d_out, fully overwritten by final GEMM
    (void)ws_size; (void)in_sizes; (void)n_in; (void)out_size;

    dim3 tb(32, 8);
    cvt_bf16_kernel<<<(BLROWS * DMODEL / 4 + 255) / 256, 256, 0, stream>>>(u, u_bf, BLROWS * DMODEL);
    // fused weight: rows 0..4111 = W_in^T, 4112..4223 = 0, 4224..6271 = W_gate^T, 6272..6399 = 0
    transpose_cvt_kernel<<<dim3(4224 / 32, DMODEL / 32), tb, 0, stream>>>(W_in, Wt_f, DMODEL, ZDIM, 4224);
    transpose_cvt_kernel<<<dim3(2176 / 32, DMODEL / 32), tb, 0, stream>>>(W_gate, Wt_f + (size_t)4224 * DMODEL, DMODEL, DINNER, 2176);
    transpose_cvt_kernel<<<dim3(DMODEL / 32, DINNER / 32), tb, 0, stream>>>(W_out, Wt_o, DINNER, DMODEL, DMODEL);

    // fused z|g GEMM: M=8192 (64 bm), K=1024 (32 slices), N=6400 (50 bn), grid 3200
    gemm_db_kernel<32, 1024, 0, 50><<<64 * 50, 256, 0, stream>>>(
        u_bf, Wt_f, z, g, dt, nullptr);

    conv_silu_kernel<<<(BLROWS * (DINNER / 8) + 255) / 256, 256, 0, stream>>>(z, conv_w, conv_b, xy);
    la_kernel<<<(BLROWS * NHEADS + 255) / 256, 256, 0, stream>>>(dt, dparam, lab);

    // chunked scan (SSD matmul form)
    chunk_state_kernel<<<BATCH * NCHUNK * NHEADS, 256, 0, stream>>>(xy, z, lab, S, Adec);
    chunk_carry_kernel<<<(BATCH * NHEADS * HEADDIM * DSTATE) / 256, 256, 0, stream>>>(S, Adec);
    chunk_y_kernel<<<BATCH * NCHUNK * NHEADS, 256, 0, stream>>>(xy, z, lab, S);

    gate_rms_kernel<<<BLROWS, 256, 0, stream>>>(xy, g, norm_w);

    // out = yn @ W_out (f32 out): M=8192 (64 bm), K=2048 (64 slices), N=1024 (8 bn), grid 512
    gemm_db_kernel<64, 2048, 1, 8><<<64 * 8, 256, 0, stream>>>(
        g, Wt_o, nullptr, nullptr, nullptr, out);
}